// Round 7
// baseline (354.727 us; speedup 1.0000x reference)
//
#include <hip/hip_runtime.h>

#define NN 4096
#define IDX_CAP 512
#define SLOPE 0.2f

typedef float f4_t __attribute__((ext_vector_type(4)));
typedef __bf16 bf8v __attribute__((ext_vector_type(8)));
typedef float f32x16 __attribute__((ext_vector_type(16)));

// ---- workspace layout (float offsets unless noted) ----
#define V_OFF     0                        // v1i,v2i,v1s,v2s : 4*128
#define C_OFF     512                      // 4 score constants
#define BT_OFF    516                      // b_total[128]
#define S_OFF     1024                     // s1i,s2i,s1s,s2s : 4*4096
#define HXI_OFF   32768                    // Ld@x   [4096,128]
#define HXS_OFF   (HXI_OFF + NN*128)       // Lu@x
#define UI_OFF    (HXS_OFF + NN*128)       // x@Wi0 + Hxi@Wi1
#define US_OFF    (UI_OFF + NN*128)        // x@Ws0 + Hxs@Ws1
#define XWH_OFF   (US_OFF + NN*128)        // REUSED: xwhT hi/lo bf16 MFMA-fragment buffers
#define OI_OFF    (XWH_OFF + NN*128)       // alpha_irr @ U_irr
#define OS_OFF    (OI_OFF + NN*128)        // alpha_sol @ U_sol
#define ZP_OFF    (OS_OFF + NN*128)        // P@xWh split-K partials: 8 * [4096,128]
#define WS_FLOATS (ZP_OFF + 8*NN*128)
#define IDX_BYTE_OFF ((size_t)WS_FLOATS * 4)                  // u16 idx lists: 2*4096*512
#define CNT_BYTE_OFF (IDX_BYTE_OFF + (size_t)2*NN*IDX_CAP*2)  // int counts: 2*4096

// Pad map for fp32 LDS GEMM tiles (4-way -> 2-way, free per m136).
#define XI(c)   ((c) + (((c) >> 5) << 2))   // [0,128) -> [0,140)

// Per-wave (row,branch) mapping, XCD-aware: blockIdx%8 = XCD; bit 2 selects
// branch so XCDs 0-3 cache branch-0 data, 4-7 branch-1. 4 rows per block.
#define BMAP_BR(bid)    (((bid) >> 2) & 1)
#define BMAP_RBLK(bid)  ((((bid) >> 3) << 2) | ((bid) & 3))   // [0,1024)

// MFMA-fragment layout for xwhT: element (col c of z, k-index k) lives at
// frag[(k>>4)*2048 + (c>>5)*512 + ((c&31) + 32*((k>>3)&1))*8 + (k&7)].
#define FRAG(c, k) ((size_t)((k) >> 4) * 2048 + (size_t)((c) >> 5) * 512 \
                    + (size_t)((((c) & 31) + 32 * (((k) >> 3) & 1)) * 8 + ((k) & 7)))

// bf16 round-to-nearest-even helpers
__device__ __forceinline__ unsigned short f2bf(float x) {
  unsigned u = __float_as_uint(x);
  return (unsigned short)((u + 0x7FFFu + ((u >> 16) & 1u)) >> 16);
}
__device__ __forceinline__ float bf2f(unsigned short h) {
  return __uint_as_float(((unsigned)h) << 16);
}
union BFU { unsigned short u[8]; bf8v v; };

// ---------------------------------------------------------------------------
// Prep: v-vectors so s1[i] = x[i,:]·v + c, b_total.
__global__ __launch_bounds__(128) void k_prep(
    const float* __restrict__ Wi_w, const float* __restrict__ Wi_b,
    const float* __restrict__ Ws_w, const float* __restrict__ Ws_b,
    const float* __restrict__ Wh_b, const float* __restrict__ att_irr,
    const float* __restrict__ att_sol, float* __restrict__ ws) {
  const int t = threadIdx.x;
  float v1i = 0.f, v2i = 0.f, v1s = 0.f, v2s = 0.f;
  for (int j = 0; j < 2; ++j) {
    for (int o = 0; o < 128; ++o) {
      const float wi = Wi_w[j*16384 + t*128 + o];
      const float wv = Ws_w[j*16384 + t*128 + o];
      v1i += wi * att_irr[j*128 + o];
      v2i += wi * att_irr[256 + j*128 + o];
      v1s += wv * att_sol[j*128 + o];
      v2s += wv * att_sol[256 + j*128 + o];
    }
  }
  ws[V_OFF + t]       = v1i;
  ws[V_OFF + 128 + t] = v2i;
  ws[V_OFF + 256 + t] = v1s;
  ws[V_OFF + 384 + t] = v2s;
  ws[BT_OFF + t] = Wi_b[t] + Wi_b[128 + t] + Ws_b[t] + Ws_b[128 + t] + Wh_b[t];
  if (t < 4) {
    const float* bb = (t < 2) ? Wi_b : Ws_b;
    const float* aa = ((t < 2) ? att_irr : att_sol) + ((t & 1) ? 256 : 0);
    float c = 0.f;
    for (int k = 0; k < 256; ++k) c += bb[k] * aa[k];
    ws[C_OFF + t] = c;
  }
}

// ---------------------------------------------------------------------------
// Fused pre-pass: blocks 0..127 compute xWh = x@Wh -> bf16 hi/lo fragment
// order (feeds k_pgemm); blocks 128..1151 compute scores.
__global__ __launch_bounds__(256) void k_pre2(
    const float* __restrict__ x, const float* __restrict__ Wh_w,
    float* __restrict__ ws, unsigned short* __restrict__ xth,
    unsigned short* __restrict__ xtl) {
  __shared__ __align__(16) float At[32][33];
  __shared__ __align__(16) float Wt[32][144];
  const int t = threadIdx.x;

  if (blockIdx.x < 128) {
    const int rb = blockIdx.x;
    const int rg = t >> 4, cg = t & 15;
    const int r0 = rb * 32;
    float acc[2][8];
    #pragma unroll
    for (int i = 0; i < 2; ++i)
      #pragma unroll
      for (int j = 0; j < 8; ++j) acc[i][j] = 0.f;
    for (int k0 = 0; k0 < 128; k0 += 32) {
      __syncthreads();
      {
        const int row = t >> 3, kq = t & 7;
        const float4 av = *(const float4*)&x[(r0 + row)*128 + k0 + kq*4];
        At[row][kq*4+0] = av.x; At[row][kq*4+1] = av.y;
        At[row][kq*4+2] = av.z; At[row][kq*4+3] = av.w;
      }
      #pragma unroll
      for (int l = 0; l < 4; ++l) {
        const int idx = t + l*256;
        const int kr = idx >> 5, c4 = idx & 31;
        const float4 wv = *(const float4*)&Wh_w[(k0 + kr)*128 + c4*4];
        *(float4*)&Wt[kr][XI(c4*4)] = wv;
      }
      __syncthreads();
      #pragma unroll
      for (int k = 0; k < 32; ++k) {
        const float a0 = At[rg*2 + 0][k];
        const float a1 = At[rg*2 + 1][k];
        const float4 b0 = *(const float4*)&Wt[k][XI(cg*8)];
        const float4 b1 = *(const float4*)&Wt[k][XI(cg*8 + 4)];
        acc[0][0] += a0*b0.x; acc[0][1] += a0*b0.y; acc[0][2] += a0*b0.z; acc[0][3] += a0*b0.w;
        acc[0][4] += a0*b1.x; acc[0][5] += a0*b1.y; acc[0][6] += a0*b1.z; acc[0][7] += a0*b1.w;
        acc[1][0] += a1*b0.x; acc[1][1] += a1*b0.y; acc[1][2] += a1*b0.z; acc[1][3] += a1*b0.w;
        acc[1][4] += a1*b1.x; acc[1][5] += a1*b1.y; acc[1][6] += a1*b1.z; acc[1][7] += a1*b1.w;
      }
    }
    #pragma unroll
    for (int i = 0; i < 2; ++i) {
      const int r = r0 + rg*2 + i;       // r = k-index of pgemm
      #pragma unroll
      for (int j = 0; j < 8; ++j) {
        const int c = cg*8 + j;          // c = output column
        const float val = acc[i][j];
        const unsigned short h = f2bf(val);
        const unsigned short l = f2bf(val - bf2f(h));
        const size_t fa = FRAG(c, r);
        xth[fa] = h;
        xtl[fa] = l;
      }
    }
  } else {
    const int wave = t >> 6, lane = t & 63;
    const int row = (blockIdx.x - 128) * 4 + wave;
    const float* v = ws + V_OFF;
    const float x0 = x[row*128 + lane];
    const float x1 = x[row*128 + 64 + lane];
    float p0 = x0 * v[lane]       + x1 * v[64 + lane];
    float p1 = x0 * v[128 + lane] + x1 * v[192 + lane];
    float p2 = x0 * v[256 + lane] + x1 * v[320 + lane];
    float p3 = x0 * v[384 + lane] + x1 * v[448 + lane];
    #pragma unroll
    for (int off = 32; off; off >>= 1) {
      p0 += __shfl_down(p0, off);
      p1 += __shfl_down(p1, off);
      p2 += __shfl_down(p2, off);
      p3 += __shfl_down(p3, off);
    }
    if (lane == 0) {
      ws[S_OFF + row]          = p0 + ws[C_OFF + 0];
      ws[S_OFF + NN + row]     = p1 + ws[C_OFF + 1];
      ws[S_OFF + 2*NN + row]   = p2 + ws[C_OFF + 2];
      ws[S_OFF + 3*NN + row]   = p3 + ws[C_OFF + 3];
    }
  }
}

// ---------------------------------------------------------------------------
// Sparse row pass v5: WAVE-INDEPENDENT. One wave per (row,branch), 4 rows per
// block, zero barriers. Chunked scan (4 x 4 nt float4) + per-wave ballot
// compaction into a private LDS slice, then per-wave float4 pair-gather and
// shfl_xor reduction. Scan/compact/gather of different rows overlap freely.
__global__ __launch_bounds__(256) void k_spmm_emit(
    const float* __restrict__ Ld, const float* __restrict__ Lu,
    const float* __restrict__ x, float* __restrict__ ws,
    unsigned short* __restrict__ idxbuf, int* __restrict__ cntbuf) {
  const int bid = blockIdx.x;
  const int br  = BMAP_BR(bid);
  const int w = threadIdx.x >> 6, lane = threadIdx.x & 63;
  const int row = BMAP_RBLK(bid) * 4 + w;
  const float* __restrict__ Lrow = (br ? Lu : Ld) + (size_t)row * NN;
  float* __restrict__ Hx = ws + (br ? HXS_OFF : HXI_OFF);
  unsigned short* __restrict__ idxg = idxbuf + (size_t)(br*NN + row) * IDX_CAP;
  const unsigned long long lmask = (1ull << lane) - 1ull;

  __shared__ short jl[4][IDX_CAP];
  __shared__ float vl[4][IDX_CAP];

  // ---- chunked scan + per-wave compaction (no barriers anywhere) ----
  const f4_t* __restrict__ Lrow4 = (const f4_t*)Lrow;
  int base = 0;
  #pragma unroll
  for (int c = 0; c < 4; ++c) {
    f4_t lv[4];
    #pragma unroll
    for (int i = 0; i < 4; ++i)
      lv[i] = __builtin_nontemporal_load(&Lrow4[c*256 + i*64 + lane]);
    #pragma unroll
    for (int i = 0; i < 4; ++i) {
      #pragma unroll
      for (int cc = 0; cc < 4; ++cc) {
        const float v = lv[i][cc];
        const unsigned long long bm = __ballot(v != 0.f);
        if (v != 0.f) {
          const int pos = base + (int)__popcll(bm & lmask);
          if (pos < IDX_CAP) {
            jl[w][pos] = (short)((c*256 + i*64 + lane)*4 + cc);
            vl[w][pos] = v;
          }
        }
        base += (int)__popcll(bm);
      }
    }
  }
  const int m = base;
  if (lane == 0) cntbuf[br*NN + row] = m;

  if (m <= IDX_CAP) {
    // emit idx list for k_attn
    for (int p = lane; p < m; p += 64) idxg[p] = (unsigned short)jl[w][p];

    // ---- per-wave pair-gather: 2 nnz per iter, unroll 4 (8 loads in flight)
    const f4_t* __restrict__ x4 = (const f4_t*)x;
    const int li = lane & 31, half = lane >> 5;
    f4_t acc = {0.f, 0.f, 0.f, 0.f};
    int p = 0;
    for (; 2*(p + 3) + 1 < m; p += 4) {
      int jj[4]; float vv[4];
      #pragma unroll
      for (int u = 0; u < 4; ++u) {
        const int q = 2*(p + u) + half;
        jj[u] = jl[w][q]; vv[u] = vl[w][q];
      }
      f4_t gg[4];
      #pragma unroll
      for (int u = 0; u < 4; ++u) gg[u] = x4[jj[u]*32 + li];
      #pragma unroll
      for (int u = 0; u < 4; ++u) acc += vv[u] * gg[u];
    }
    for (; 2*p < m; ++p) {
      const int q = 2*p + half;
      if (q < m) acc += vl[w][q] * x4[jl[w][q]*32 + li];
    }
    #pragma unroll
    for (int c = 0; c < 4; ++c) acc[c] += __shfl_xor(acc[c], 32);
    if (half == 0) *(f4_t*)&Hx[row*128 + li*4] = acc;
  } else {
    // overflow fallback (statistically impossible at 5%): per-wave dense
    const float2* __restrict__ x2 = (const float2*)x;
    float acc0 = 0.f, acc1 = 0.f;
    for (int j = 0; j < NN; ++j) {
      const float v = Lrow[j];
      if (v != 0.f) {
        const float2 g = x2[j*64 + lane];
        acc0 += v*g.x; acc1 += v*g.y;
      }
    }
    Hx[row*128 + lane*2]     = acc0;
    Hx[row*128 + lane*2 + 1] = acc1;
  }
}

// ---------------------------------------------------------------------------
// U-GEMMs: U_irr = x@Wi0 + Hxi@Wi1 ; U_sol = x@Ws0 + Hxs@Ws1 (padded Wt).
__global__ __launch_bounds__(256) void k_ugemm(
    const float* __restrict__ x, const float* __restrict__ Wi_w,
    const float* __restrict__ Ws_w, float* __restrict__ ws) {
  const int rb = blockIdx.x;
  const int sel = blockIdx.y;      // 0:U_irr 1:U_sol
  const float* A[2]; const float* W[2]; float* out;
  if (sel == 0) { A[0]=x; W[0]=Wi_w; A[1]=ws+HXI_OFF; W[1]=Wi_w+16384; out=ws+UI_OFF; }
  else          { A[0]=x; W[0]=Ws_w; A[1]=ws+HXS_OFF; W[1]=Ws_w+16384; out=ws+US_OFF; }

  __shared__ __align__(16) float At[32][33];
  __shared__ __align__(16) float Wt[32][144];
  const int t = threadIdx.x;
  const int rg = t >> 4, cg = t & 15;
  const int r0 = rb * 32;
  float acc[2][8];
  #pragma unroll
  for (int i = 0; i < 2; ++i)
    #pragma unroll
    for (int j = 0; j < 8; ++j) acc[i][j] = 0.f;

  for (int ps = 0; ps < 2; ++ps) {
    const float* __restrict__ Ap = A[ps];
    const float* __restrict__ Wp = W[ps];
    for (int k0 = 0; k0 < 128; k0 += 32) {
      __syncthreads();
      {
        const int row = t >> 3, kq = t & 7;
        const float4 av = *(const float4*)&Ap[(r0 + row)*128 + k0 + kq*4];
        At[row][kq*4+0] = av.x; At[row][kq*4+1] = av.y;
        At[row][kq*4+2] = av.z; At[row][kq*4+3] = av.w;
      }
      #pragma unroll
      for (int l = 0; l < 4; ++l) {
        const int idx = t + l*256;
        const int kr = idx >> 5, c4 = idx & 31;
        const float4 wv = *(const float4*)&Wp[(k0 + kr)*128 + c4*4];
        *(float4*)&Wt[kr][XI(c4*4)] = wv;
      }
      __syncthreads();
      #pragma unroll
      for (int k = 0; k < 32; ++k) {
        const float a0 = At[rg*2 + 0][k];
        const float a1 = At[rg*2 + 1][k];
        const float4 b0 = *(const float4*)&Wt[k][XI(cg*8)];
        const float4 b1 = *(const float4*)&Wt[k][XI(cg*8 + 4)];
        acc[0][0] += a0*b0.x; acc[0][1] += a0*b0.y; acc[0][2] += a0*b0.z; acc[0][3] += a0*b0.w;
        acc[0][4] += a0*b1.x; acc[0][5] += a0*b1.y; acc[0][6] += a0*b1.z; acc[0][7] += a0*b1.w;
        acc[1][0] += a1*b0.x; acc[1][1] += a1*b0.y; acc[1][2] += a1*b0.z; acc[1][3] += a1*b0.w;
        acc[1][4] += a1*b1.x; acc[1][5] += a1*b1.y; acc[1][6] += a1*b1.z; acc[1][7] += a1*b1.w;
      }
    }
  }
  #pragma unroll
  for (int i = 0; i < 2; ++i) {
    const int r = r0 + rg*2 + i;
    #pragma unroll
    for (int j = 0; j < 8; ++j) out[r*128 + cg*8 + j] = acc[i][j];
  }
}

// ---------------------------------------------------------------------------
// Masked-softmax attention v5: WAVE-INDEPENDENT, one wave per (row,branch),
// zero barriers. Per-wave exp + shfl denominator + pair-gather.
__global__ __launch_bounds__(256) void k_attn(
    const float* __restrict__ Ld, const float* __restrict__ Lu,
    float* __restrict__ ws, const unsigned short* __restrict__ idxbuf,
    const int* __restrict__ cntbuf) {
  const int bid = blockIdx.x;
  const int br  = BMAP_BR(bid);
  const int w = threadIdx.x >> 6, lane = threadIdx.x & 63;
  const int row = BMAP_RBLK(bid) * 4 + w;
  const float* __restrict__ U = ws + (br ? US_OFF : UI_OFF);
  float* __restrict__ O = ws + (br ? OS_OFF : OI_OFF);
  const float s1 = ws[S_OFF + (br ? 2*NN : 0) + row];
  const float* __restrict__ s2a = ws + S_OFF + (br ? 3*NN : NN);
  const int cnt = cntbuf[br*NN + row];

  __shared__ short jl[4][IDX_CAP];
  __shared__ float el[4][IDX_CAP];

  if (cnt > 0 && cnt <= IDX_CAP) {
    const unsigned short* __restrict__ idx = idxbuf + (size_t)(br*NN + row) * IDX_CAP;
    float dpart = 0.f;
    for (int p = lane; p < cnt; p += 64) {
      const int j = idx[p];
      const float sc = s1 + s2a[j];
      const float e = expf(sc >= 0.f ? sc : SLOPE * sc);
      jl[w][p] = (short)j; el[w][p] = e; dpart += e;
    }
    #pragma unroll
    for (int off = 32; off; off >>= 1) dpart += __shfl_xor(dpart, off);
    const float rden = 1.f / dpart;

    const f4_t* __restrict__ U4 = (const f4_t*)U;
    const int li = lane & 31, half = lane >> 5;
    f4_t acc = {0.f, 0.f, 0.f, 0.f};
    int p = 0;
    for (; 2*(p + 3) + 1 < cnt; p += 4) {
      int jj[4]; float ee[4];
      #pragma unroll
      for (int u = 0; u < 4; ++u) {
        const int q = 2*(p + u) + half;
        jj[u] = jl[w][q]; ee[u] = el[w][q];
      }
      f4_t gg[4];
      #pragma unroll
      for (int u = 0; u < 4; ++u) gg[u] = U4[jj[u]*32 + li];
      #pragma unroll
      for (int u = 0; u < 4; ++u) acc += ee[u] * gg[u];
    }
    for (; 2*p < cnt; ++p) {
      const int q = 2*p + half;
      if (q < cnt) acc += el[w][q] * U4[jl[w][q]*32 + li];
    }
    #pragma unroll
    for (int c = 0; c < 4; ++c) acc[c] += __shfl_xor(acc[c], 32);
    if (half == 0) {
      acc *= rden;
      *(f4_t*)&O[row*128 + li*4] = acc;
    }
  } else if (cnt == 0) {
    // all-masked row -> uniform 1/N (never hit at 5%)
    const float2* __restrict__ U2 = (const float2*)U;
    float acc0 = 0.f, acc1 = 0.f;
    for (int j = 0; j < NN; ++j) {
      const float2 g = U2[j*64 + lane];
      acc0 += g.x; acc1 += g.y;
    }
    O[row*128 + lane*2]     = acc0 * (1.f / NN);
    O[row*128 + lane*2 + 1] = acc1 * (1.f / NN);
  } else {
    // overflowed index cap: per-wave dense rescan
    const float* __restrict__ Lrow = (br ? Lu : Ld) + (size_t)row * NN;
    const float2* __restrict__ U2 = (const float2*)U;
    float acc0 = 0.f, acc1 = 0.f, dp = 0.f;
    for (int j = 0; j < NN; ++j) {
      const float v = Lrow[j];
      if (v != 0.f) {
        const float sc = s1 + s2a[j];
        const float e = expf(sc >= 0.f ? sc : SLOPE * sc);
        const float2 g = U2[j*64 + lane];
        acc0 += e*g.x; acc1 += e*g.y;
        dp += e;
      }
    }
    // dp is identical across lanes (each lane accumulated every nnz)
    O[row*128 + lane*2]     = acc0 / dp;
    O[row*128 + lane*2 + 1] = acc1 / dp;
  }
}

// ---------------------------------------------------------------------------
// Dense P @ xWh via MFMA (round-6 form): BM=32, grid (128,8), fragment-
// ordered B, nt A-loads with one-step prefetch.
__global__ __launch_bounds__(256) void k_pgemm(
    const float* __restrict__ P, const unsigned short* __restrict__ xth,
    const unsigned short* __restrict__ xtl, float* __restrict__ zpart) {
  const int t = threadIdx.x;
  const int w = t >> 6, lane = t & 63;
  const int la = lane & 31;
  const int koff = (lane >> 5) * 8;
  const int r0 = blockIdx.x * 32;
  const int kz = blockIdx.y;
  const int kb = kz * 512 + w * 128;     // this wave's 128-wide K-quarter

  f32x16 acc[4];
  #pragma unroll
  for (int n = 0; n < 4; ++n)
    #pragma unroll
    for (int e = 0; e < 16; ++e) acc[n][e] = 0.f;

  const float* __restrict__ arow = P + (size_t)(r0 + la) * NN + kb + koff;
  const unsigned short* __restrict__ bh_base = xth + (size_t)kb * 128 + lane * 8;
  const unsigned short* __restrict__ bl_base = xtl + (size_t)kb * 128 + lane * 8;

  f4_t a0 = __builtin_nontemporal_load((const f4_t*)arow);
  f4_t a1 = __builtin_nontemporal_load((const f4_t*)(arow + 4));
  for (int s = 0; s < 8; ++s) {
    f4_t na0 = a0, na1 = a1;
    if (s < 7) {
      na0 = __builtin_nontemporal_load((const f4_t*)(arow + (s + 1) * 16));
      na1 = __builtin_nontemporal_load((const f4_t*)(arow + (s + 1) * 16 + 4));
    }
    BFU ah, al;
    #pragma unroll
    for (int i = 0; i < 8; ++i) {
      const float f = (i < 4) ? a0[i] : a1[i - 4];
      const unsigned short h = f2bf(f);
      ah.u[i] = h;
      al.u[i] = f2bf(f - bf2f(h));
    }
    const unsigned short* __restrict__ bh_s = bh_base + s * 2048;
    const unsigned short* __restrict__ bl_s = bl_base + s * 2048;
    #pragma unroll
    for (int n = 0; n < 4; ++n) {
      const bf8v bh = *(const bf8v*)(bh_s + n * 512);
      const bf8v bl = *(const bf8v*)(bl_s + n * 512);
      acc[n] = __builtin_amdgcn_mfma_f32_32x32x16_bf16(ah.v, bh, acc[n], 0, 0, 0);
      acc[n] = __builtin_amdgcn_mfma_f32_32x32x16_bf16(al.v, bh, acc[n], 0, 0, 0);
      acc[n] = __builtin_amdgcn_mfma_f32_32x32x16_bf16(ah.v, bl, acc[n], 0, 0, 0);
    }
    a0 = na0; a1 = na1;
  }

  __shared__ float red[2][32][128];
  if (w < 2) {
    #pragma unroll
    for (int n = 0; n < 4; ++n)
      #pragma unroll
      for (int reg = 0; reg < 16; ++reg) {
        const int row = (reg & 3) + 8*(reg >> 2) + 4*(lane >> 5);
        red[w][row][32*n + la] = acc[n][reg];
      }
  }
  __syncthreads();
  if (w >= 2) {
    #pragma unroll
    for (int n = 0; n < 4; ++n)
      #pragma unroll
      for (int reg = 0; reg < 16; ++reg) {
        const int row = (reg & 3) + 8*(reg >> 2) + 4*(lane >> 5);
        red[w - 2][row][32*n + la] += acc[n][reg];
      }
  }
  __syncthreads();
  float* __restrict__ zp = zpart + (size_t)kz * NN * 128;
  #pragma unroll
  for (int i = 0; i < 8; ++i) {
    const int row = w * 8 + i;
    zp[(size_t)(r0 + row) * 128 + lane]      = red[0][row][lane]      + red[1][row][lane];
    zp[(size_t)(r0 + row) * 128 + 64 + lane] = red[0][row][64 + lane] + red[1][row][64 + lane];
  }
}

// ---------------------------------------------------------------------------
// z = O_irr + O_sol + sum_k zpart[k] + b_total
__global__ __launch_bounds__(256) void k_combine(const float* __restrict__ ws,
                                                 float* __restrict__ z) {
  const int i = blockIdx.x * 256 + threadIdx.x;
  const int col = i & 127;
  float acc = ws[BT_OFF + col] + ws[OI_OFF + i] + ws[OS_OFF + i];
  #pragma unroll
  for (int kz = 0; kz < 8; ++kz) acc += ws[ZP_OFF + kz*NN*128 + i];
  z[i] = acc;
}

// ---------------------------------------------------------------------------
extern "C" void kernel_launch(void* const* d_in, const int* in_sizes, int n_in,
                              void* d_out, int out_size, void* d_ws, size_t ws_size,
                              hipStream_t stream) {
  const float* x       = (const float*)d_in[0];
  const float* Lu      = (const float*)d_in[1];
  const float* Ld      = (const float*)d_in[2];
  const float* P       = (const float*)d_in[3];
  const float* Wi_w    = (const float*)d_in[4];
  const float* Wi_b    = (const float*)d_in[5];
  const float* Ws_w    = (const float*)d_in[6];
  const float* Ws_b    = (const float*)d_in[7];
  const float* Wh_w    = (const float*)d_in[8];
  const float* Wh_b    = (const float*)d_in[9];
  const float* att_irr = (const float*)d_in[10];
  const float* att_sol = (const float*)d_in[11];
  float* z  = (float*)d_out;
  float* ws = (float*)d_ws;
  unsigned short* idxbuf = (unsigned short*)((char*)d_ws + IDX_BYTE_OFF);
  int*            cntbuf = (int*)((char*)d_ws + CNT_BYTE_OFF);
  float*          zpart  = ws + ZP_OFF;
  unsigned short* xth    = (unsigned short*)(ws + XWH_OFF);           // 1 MB
  unsigned short* xtl    = xth + (size_t)128 * NN;                    // 1 MB

  k_prep<<<1, 128, 0, stream>>>(Wi_w, Wi_b, Ws_w, Ws_b, Wh_b, att_irr, att_sol, ws);
  k_pre2<<<1152, 256, 0, stream>>>(x, Wh_w, ws, xth, xtl);
  k_spmm_emit<<<2 * NN / 4, 256, 0, stream>>>(Ld, Lu, x, ws, idxbuf, cntbuf);
  {
    dim3 g(128, 2);
    k_ugemm<<<g, 256, 0, stream>>>(x, Wi_w, Ws_w, ws);
  }
  k_attn<<<2 * NN / 4, 256, 0, stream>>>(Ld, Lu, ws, idxbuf, cntbuf);
  {
    dim3 g(128, 8);
    k_pgemm<<<g, 256, 0, stream>>>(P, xth, xtl, zpart);
  }
  k_combine<<<NN * 128 / 256, 256, 0, stream>>>(ws, z);
}